// Round 5
// baseline (249.824 us; speedup 1.0000x reference)
//
#include <hip/hip_runtime.h>
#include <stdint.h>

typedef unsigned short u16;
typedef __attribute__((ext_vector_type(8))) short short8;
typedef __attribute__((ext_vector_type(4))) float floatx4;
typedef __attribute__((ext_vector_type(4))) unsigned short u16x4;

__device__ __forceinline__ float bf2f(u16 v) {
  union { uint32_t u; float f; } x; x.u = ((uint32_t)v) << 16; return x.f;
}
__device__ __forceinline__ u16 f2bf(float f) {
  union { float f; uint32_t u; } x; x.f = f;
  uint32_t r = x.u + 0x7fffu + ((x.u >> 16) & 1u);
  return (u16)(r >> 16);
}

#define GL2LDS(g, l)                                                          \
  __builtin_amdgcn_global_load_lds(                                           \
      (const __attribute__((address_space(1))) void*)(g),                     \
      (__attribute__((address_space(3))) void*)(l), 16, 0, 0)

// ------- transpose weights: fp32 in (R x C) -> bf16 out (C x R) ----------------
__global__ __launch_bounds__(256) void transpose_w_k(const float* __restrict__ in,
                                                     u16* __restrict__ out,
                                                     int R, int C) {
  __shared__ float tile[32][33];
  int c0 = blockIdx.x * 32, r0 = blockIdx.y * 32;
  int tx = threadIdx.x, ty = threadIdx.y;
#pragma unroll
  for (int i = 0; i < 32; i += 8)
    tile[ty + i][tx] = in[(size_t)(r0 + ty + i) * C + c0 + tx];
  __syncthreads();
#pragma unroll
  for (int i = 0; i < 32; i += 8)
    out[(size_t)(c0 + ty + i) * R + r0 + tx] = f2bf(tile[tx][ty + i]);
}

// ------- layernorm: 4096 rows x 1024, fp32 in -> bf16 out ----------------------
__global__ __launch_bounds__(256) void layernorm_k(const float* __restrict__ x,
                                                   const float* __restrict__ gamma,
                                                   const float* __restrict__ beta,
                                                   u16* __restrict__ xn) {
  int row = blockIdx.x;
  int t = threadIdx.x;
  const float* xr = x + (size_t)row * 1024;
  float4 xv = *(const float4*)(xr + t * 4);
  float v0 = xv.x, v1 = xv.y, v2 = xv.z, v3 = xv.w;
  float s = v0 + v1 + v2 + v3;
  float s2 = v0 * v0 + v1 * v1 + v2 * v2 + v3 * v3;
#pragma unroll
  for (int d = 1; d < 64; d <<= 1) {
    s += __shfl_xor(s, d, 64);
    s2 += __shfl_xor(s2, d, 64);
  }
  __shared__ float red[8];
  int lane = t & 63, wv = t >> 6;
  if (lane == 0) { red[wv] = s; red[4 + wv] = s2; }
  __syncthreads();
  s = red[0] + red[1] + red[2] + red[3];
  s2 = red[4] + red[5] + red[6] + red[7];
  float mu = s * (1.0f / 1024.0f);
  float var = s2 * (1.0f / 1024.0f) - mu * mu;
  float rstd = rsqrtf(var + 1e-5f);
  float4 gv = *(const float4*)(gamma + t * 4);
  float4 bv = *(const float4*)(beta + t * 4);
  u16x4 ov;
  ov.x = f2bf((v0 - mu) * rstd * gv.x + bv.x);
  ov.y = f2bf((v1 - mu) * rstd * gv.y + bv.y);
  ov.z = f2bf((v2 - mu) * rstd * gv.z + bv.z);
  ov.w = f2bf((v3 - mu) * rstd * gv.w + bv.w);
  *(u16x4*)(xn + (size_t)row * 1024 + t * 4) = ov;
}

// ------- GEMM: C[MxN] = A[MxK](bf16,lda) * BT[NxK](bf16)^T ---------------------
__global__ __launch_bounds__(256) void gemm_bf16_k(const u16* __restrict__ A,
                                                   const u16* __restrict__ BT,
                                                   void* __restrict__ Cp,
                                                   int K, int lda, int ldc,
                                                   int f32out) {
  __shared__ __align__(16) u16 lA[128 * 32];
  __shared__ __align__(16) u16 lB[128 * 32];
  int tid = threadIdx.x;
  int bm = blockIdx.y * 128;
  int bn = blockIdx.x * 128;
  int w = tid >> 6, l = tid & 63;
  int wm = (w >> 1) * 64, wn = (w & 1) * 64;
  int lr = l & 15, lq = l >> 4;
  floatx4 acc[4][4] = {};
  int sr = w * 16 + (l >> 2);
  int sc = (l & 3) * 8;
  for (int k0 = 0; k0 < K; k0 += 32) {
    GL2LDS(A + (size_t)(bm + sr) * lda + k0 + sc, &lA[sr * 32 + sc]);
    GL2LDS(A + (size_t)(bm + sr + 64) * lda + k0 + sc, &lA[(sr + 64) * 32 + sc]);
    GL2LDS(BT + (size_t)(bn + sr) * K + k0 + sc, &lB[sr * 32 + sc]);
    GL2LDS(BT + (size_t)(bn + sr + 64) * K + k0 + sc, &lB[(sr + 64) * 32 + sc]);
    __syncthreads();
    short8 afr[4], bfr[4];
#pragma unroll
    for (int i = 0; i < 4; i++)
      afr[i] = *(const short8*)(&lA[(wm + i * 16 + lr) * 32 + lq * 8]);
#pragma unroll
    for (int i = 0; i < 4; i++)
      bfr[i] = *(const short8*)(&lB[(wn + i * 16 + lr) * 32 + lq * 8]);
#pragma unroll
    for (int mi = 0; mi < 4; mi++)
#pragma unroll
      for (int ni = 0; ni < 4; ni++)
        acc[mi][ni] = __builtin_amdgcn_mfma_f32_16x16x32_bf16(
            afr[mi], bfr[ni], acc[mi][ni], 0, 0, 0);
    __syncthreads();
  }
  if (f32out) {
    float* Cf = (float*)Cp;
#pragma unroll
    for (int mi = 0; mi < 4; mi++)
#pragma unroll
      for (int ni = 0; ni < 4; ni++)
#pragma unroll
        for (int r = 0; r < 4; r++) {
          int row = bm + wm + mi * 16 + lq * 4 + r;
          int col = bn + wn + ni * 16 + lr;
          Cf[(size_t)row * ldc + col] = acc[mi][ni][r];
        }
  } else {
    u16* Cb = (u16*)Cp;
#pragma unroll
    for (int mi = 0; mi < 4; mi++)
#pragma unroll
      for (int ni = 0; ni < 4; ni++)
#pragma unroll
        for (int r = 0; r < 4; r++) {
          int row = bm + wm + mi * 16 + lq * 4 + r;
          int col = bn + wn + ni * 16 + lr;
          Cb[(size_t)row * ldc + col] = f2bf(acc[mi][ni][r]);
        }
  }
}

// ------- RoPE (in-place, vectorized) + q scale (x 0.125 x log2e) ---------------
// thread handles 4 consecutive i and their +32 pairs for q and k.
__global__ __launch_bounds__(256) void rope_inplace_k(u16* __restrict__ qkv) {
  int idx = blockIdx.x * 256 + threadIdx.x;  // (row*16 + h)*8 + ig
  int ig = idx & 7;
  int h = (idx >> 3) & 15;
  int row = idx >> 7;
  int n = row & 2047;
  int i0 = ig * 4;
  const float QS = 0.125f * 1.44269504088896f;  // fold log2e for exp2 softmax
  float c_[4], s_[4];
  float invf = exp2f(-(float)i0 * 0.4152410118609203f);
  const float rstep = 0.74989420933245582f;  // 10000^(-1/32)
#pragma unroll
  for (int e = 0; e < 4; e++) {
    float ang = (float)n * invf;
    c_[e] = cosf(ang);
    s_[e] = sinf(ang);
    invf *= rstep;
  }
  size_t base = (size_t)row * 3072 + h * 64 + i0;
  u16x4 qlo = *(u16x4*)(qkv + base);
  u16x4 qhi = *(u16x4*)(qkv + base + 32);
  u16x4 klo = *(u16x4*)(qkv + base + 1024);
  u16x4 khi = *(u16x4*)(qkv + base + 1056);
  u16x4 oqlo, oqhi, oklo, okhi;
#pragma unroll
  for (int e = 0; e < 4; e++) {
    float x1 = bf2f(((u16*)&qlo)[e]), x2 = bf2f(((u16*)&qhi)[e]);
    ((u16*)&oqlo)[e] = f2bf((x1 * c_[e] - x2 * s_[e]) * QS);
    ((u16*)&oqhi)[e] = f2bf((x2 * c_[e] + x1 * s_[e]) * QS);
    x1 = bf2f(((u16*)&klo)[e]); x2 = bf2f(((u16*)&khi)[e]);
    ((u16*)&oklo)[e] = f2bf(x1 * c_[e] - x2 * s_[e]);
    ((u16*)&okhi)[e] = f2bf(x2 * c_[e] + x1 * s_[e]);
  }
  *(u16x4*)(qkv + base) = oqlo;
  *(u16x4*)(qkv + base + 32) = oqhi;
  *(u16x4*)(qkv + base + 1024) = oklo;
  *(u16x4*)(qkv + base + 1056) = okhi;
}

// ------- V transpose: qkv v-slice (n,64) -> vT (bh, 64, n), bf16 ---------------
__global__ __launch_bounds__(256) void transpose_v_k(const u16* __restrict__ qkv,
                                                     u16* __restrict__ vT) {
  __shared__ u16 tile[32][33];
  int bh = blockIdx.z;
  int b = bh >> 4, h = bh & 15;
  int n0 = blockIdx.x * 32, d0 = blockIdx.y * 32;
  int tx = threadIdx.x, ty = threadIdx.y;
#pragma unroll
  for (int i = 0; i < 32; i += 8)
    tile[ty + i][tx] =
        qkv[(size_t)(b * 2048 + n0 + ty + i) * 3072 + 2048 + h * 64 + d0 + tx];
  __syncthreads();
#pragma unroll
  for (int i = 0; i < 32; i += 8)
    vT[((size_t)bh * 64 + d0 + ty + i) * 2048 + n0 + tx] = tile[tx][ty + i];
}

// ------- flash attention (causal), exp2 domain ---------------------------------
// 1024 blocks x 128 thr: block (p, s): tile A rows [64p+32s, +32), tile B rows
// [64(31-p)+32s, +32); 2 waves x 16 rows each. K/V staged via global_load_lds
// into XOR-swizzled unpadded LDS (phys col8 = col8 ^ (row&7)).
#define LPT 72
__device__ __forceinline__ void attn_tile(const u16* lK, const u16* lV, u16* lp,
                                          const short8* aq, floatx4* o,
                                          float* m_i, float* l_i, int lr, int lq,
                                          bool diag, int qbase, int k0g) {
  floatx4 s[4];
#pragma unroll
  for (int ni = 0; ni < 4; ni++) {
    floatx4 accs = {};
#pragma unroll
    for (int kc = 0; kc < 2; kc++) {
      int R = ni * 16 + lr;
      int c8 = (kc * 4 + lq) ^ (R & 7);
      short8 bf = *(const short8*)&lK[R * 64 + c8 * 8];
      accs = __builtin_amdgcn_mfma_f32_16x16x32_bf16(aq[kc], bf, accs, 0, 0, 0);
    }
    s[ni] = accs;
  }
  if (diag) {
#pragma unroll
    for (int ni = 0; ni < 4; ni++) {
      int kg = k0g + ni * 16 + lr;
#pragma unroll
      for (int r = 0; r < 4; r++) {
        int qg = qbase + lq * 4 + r;
        if (kg > qg) s[ni][r] = -1e30f;
      }
    }
  }
  float mnew[4], alpha[4], psum[4];
#pragma unroll
  for (int r = 0; r < 4; r++) {
    float mx = fmaxf(fmaxf(s[0][r], s[1][r]), fmaxf(s[2][r], s[3][r]));
#pragma unroll
    for (int d = 1; d < 16; d <<= 1) mx = fmaxf(mx, __shfl_xor(mx, d, 64));
    mnew[r] = fmaxf(m_i[r], mx);
    alpha[r] = exp2f(m_i[r] - mnew[r]);
    psum[r] = 0.0f;
  }
#pragma unroll
  for (int ni = 0; ni < 4; ni++)
#pragma unroll
    for (int r = 0; r < 4; r++) {
      float p = exp2f(s[ni][r] - mnew[r]);
      union { float f; uint32_t u; } cv; cv.f = p;
      u16 pb = (u16)(cv.u >> 16);  // truncate to bf16
      lp[(lq * 4 + r) * LPT + ni * 16 + lr] = pb;
      psum[r] += bf2f(pb);         // consistent with stored P
    }
#pragma unroll
  for (int r = 0; r < 4; r++) {
#pragma unroll
    for (int d = 1; d < 16; d <<= 1) psum[r] += __shfl_xor(psum[r], d, 64);
    l_i[r] = l_i[r] * alpha[r] + psum[r];
    m_i[r] = mnew[r];
  }
#pragma unroll
  for (int di = 0; di < 4; di++)
#pragma unroll
    for (int r = 0; r < 4; r++) o[di][r] *= alpha[r];
  short8 pa0 = *(const short8*)&lp[lr * LPT + lq * 8];
  short8 pa1 = *(const short8*)&lp[lr * LPT + 32 + lq * 8];
#pragma unroll
  for (int di = 0; di < 4; di++) {
    int R = di * 16 + lr;
    int c80 = lq ^ (R & 7);
    int c81 = (4 + lq) ^ (R & 7);
    short8 bv0 = *(const short8*)&lV[R * 64 + c80 * 8];
    o[di] = __builtin_amdgcn_mfma_f32_16x16x32_bf16(pa0, bv0, o[di], 0, 0, 0);
    short8 bv1 = *(const short8*)&lV[R * 64 + c81 * 8];
    o[di] = __builtin_amdgcn_mfma_f32_16x16x32_bf16(pa1, bv1, o[di], 0, 0, 0);
  }
}

__global__ __launch_bounds__(128) void attn_k(const u16* __restrict__ qkv,
                                              const u16* __restrict__ vt,
                                              u16* __restrict__ out) {
  __shared__ __align__(16) u16 lK[64 * 64];
  __shared__ __align__(16) u16 lV[64 * 64];
  __shared__ __align__(16) u16 lP[2][16 * LPT];
  int bh = blockIdx.y;
  int b = bh >> 4, h = bh & 15;
  int p = blockIdx.x >> 1;
  int sh = blockIdx.x & 1;
  int jB = 31 - p;
  int tid = threadIdx.x;
  int w = tid >> 6, l = tid & 63;
  int lr = l & 15, lq = l >> 4;
  int q0A = p * 64 + sh * 32 + w * 16;
  int q0B = jB * 64 + sh * 32 + w * 16;
  const u16* qb = qkv + (size_t)b * 2048 * 3072 + h * 64;
  const u16* kb = qkv + (size_t)b * 2048 * 3072 + 1024 + h * 64;
  const u16* vb = vt + (size_t)bh * 64 * 2048;
  short8 aqA[2], aqB[2];
  aqA[0] = *(const short8*)(qb + (size_t)(q0A + lr) * 3072 + lq * 8);
  aqA[1] = *(const short8*)(qb + (size_t)(q0A + lr) * 3072 + 32 + lq * 8);
  aqB[0] = *(const short8*)(qb + (size_t)(q0B + lr) * 3072 + lq * 8);
  aqB[1] = *(const short8*)(qb + (size_t)(q0B + lr) * 3072 + 32 + lq * 8);
  floatx4 oA[4] = {}, oB[4] = {};
  float mA[4], lA_[4], mB[4], lB_[4];
#pragma unroll
  for (int r = 0; r < 4; r++) {
    mA[r] = -1e30f; lA_[r] = 0.0f; mB[r] = -1e30f; lB_[r] = 0.0f;
  }
  // staging: swizzled source col8 so LDS ends up phys col8 = col8 ^ (row&7)
  int srow8 = l >> 3;                 // row within 8-row chunk
  int sc8 = (l & 7) ^ srow8;          // source col8 for this lane
  u16* lp = &lP[w][0];
  for (int kt = 0; kt <= jB; ++kt) {
#pragma unroll
    for (int c = 0; c < 4; c++) {
      int m = w * 4 + c;              // 8-row chunk index
      int row = m * 8 + srow8;
      GL2LDS(kb + (size_t)(kt * 64 + row) * 3072 + sc8 * 8, &lK[m * 512]);
      GL2LDS(vb + (size_t)row * 2048 + kt * 64 + sc8 * 8, &lV[m * 512]);
    }
    __syncthreads();
    attn_tile(lK, lV, lp, aqB, oB, mB, lB_, lr, lq, kt == jB, q0B, kt * 64);
    if (kt <= p)
      attn_tile(lK, lV, lp, aqA, oA, mA, lA_, lr, lq, kt == p, q0A, kt * 64);
    __syncthreads();
  }
#pragma unroll
  for (int di = 0; di < 4; di++)
#pragma unroll
    for (int r = 0; r < 4; r++) {
      int qgA = q0A + lq * 4 + r;
      int qgB = q0B + lq * 4 + r;
      out[((size_t)(b * 2048 + qgA)) * 3072 + h * 64 + di * 16 + lr] =
          f2bf(oA[di][r] / lA_[r]);
      out[((size_t)(b * 2048 + qgB)) * 3072 + h * 64 + di * 16 + lr] =
          f2bf(oB[di][r] / lB_[r]);
    }
}

// ------- launch ---------------------------------------------------------------
extern "C" void kernel_launch(void* const* d_in, const int* in_sizes, int n_in,
                              void* d_out, int out_size, void* d_ws, size_t ws_size,
                              hipStream_t stream) {
  const float* x = (const float*)d_in[0];
  const float* gamma = (const float*)d_in[1];
  const float* beta = (const float*)d_in[2];
  const float* Wq = (const float*)d_in[3];
  const float* Wkv = (const float*)d_in[4];
  const float* Wo = (const float*)d_in[5];
  float* out = (float*)d_out;
  char* ws = (char*)d_ws;

  u16* qkv = (u16*)(ws);               // 4096x3072 bf16 = 24 MiB
  u16* wqkvT = (u16*)(ws + 25165824);  // 3072x1024 = 6 MiB
  u16* woT = (u16*)(ws + 31457280);    // 1024x1024 = 2 MiB
  u16* xn = (u16*)(ws + 33554432);     // 4096x1024 = 8 MiB
  u16* vT = xn;                        // alias: xn dead after GEMM1
  u16* attn_out = qkv + 2048;          // v-slice of qkv (dead after transpose_v)

  dim3 tb32(32, 8);
  transpose_w_k<<<dim3(32, 32), tb32, 0, stream>>>(Wq, wqkvT, 1024, 1024);
  transpose_w_k<<<dim3(64, 32), tb32, 0, stream>>>(Wkv, wqkvT + 1024 * 1024, 1024, 2048);
  transpose_w_k<<<dim3(32, 32), tb32, 0, stream>>>(Wo, woT, 1024, 1024);
  layernorm_k<<<4096, 256, 0, stream>>>(x, gamma, beta, xn);
  gemm_bf16_k<<<dim3(24, 32), 256, 0, stream>>>(xn, wqkvT, qkv, 1024, 1024, 3072, 0);
  rope_inplace_k<<<2048, 256, 0, stream>>>(qkv);
  transpose_v_k<<<dim3(64, 2, 32), tb32, 0, stream>>>(qkv, vT);
  attn_k<<<dim3(32, 32), 128, 0, stream>>>(qkv, vT, attn_out);
  gemm_bf16_k<<<dim3(8, 32), 256, 0, stream>>>(attn_out, woT, out, 1024, 3072, 1024, 1);
}

// Round 6
// 218.059 us; speedup vs baseline: 1.1457x; 1.1457x over previous
//
#include <hip/hip_runtime.h>
#include <stdint.h>

typedef unsigned short u16;
typedef __attribute__((ext_vector_type(8))) short short8;
typedef __attribute__((ext_vector_type(4))) float floatx4;
typedef __attribute__((ext_vector_type(4))) unsigned short u16x4;
typedef __attribute__((ext_vector_type(2))) unsigned int uint2v;

__device__ __forceinline__ float bf2f(u16 v) {
  union { uint32_t u; float f; } x; x.u = ((uint32_t)v) << 16; return x.f;
}
__device__ __forceinline__ u16 f2bf(float f) {
  union { float f; uint32_t u; } x; x.f = f;
  uint32_t r = x.u + 0x7fffu + ((x.u >> 16) & 1u);
  return (u16)(r >> 16);
}
__device__ __forceinline__ uint32_t fu(float f) {
  union { float f; uint32_t u; } x; x.f = f; return x.u;
}

#define GL2LDS(g, l)                                                          \
  __builtin_amdgcn_global_load_lds(                                           \
      (const __attribute__((address_space(1))) void*)(g),                     \
      (__attribute__((address_space(3))) void*)(l), 16, 0, 0)

// ------- transpose weights: fp32 in (R x C) -> bf16 out (C x R) ----------------
__global__ __launch_bounds__(256) void transpose_w_k(const float* __restrict__ in,
                                                     u16* __restrict__ out,
                                                     int R, int C) {
  __shared__ float tile[32][33];
  int c0 = blockIdx.x * 32, r0 = blockIdx.y * 32;
  int tx = threadIdx.x, ty = threadIdx.y;
#pragma unroll
  for (int i = 0; i < 32; i += 8)
    tile[ty + i][tx] = in[(size_t)(r0 + ty + i) * C + c0 + tx];
  __syncthreads();
#pragma unroll
  for (int i = 0; i < 32; i += 8)
    out[(size_t)(c0 + ty + i) * R + r0 + tx] = f2bf(tile[tx][ty + i]);
}

// ------- layernorm: 4096 rows x 1024, fp32 in -> bf16 out ----------------------
__global__ __launch_bounds__(256) void layernorm_k(const float* __restrict__ x,
                                                   const float* __restrict__ gamma,
                                                   const float* __restrict__ beta,
                                                   u16* __restrict__ xn) {
  int row = blockIdx.x;
  int t = threadIdx.x;
  const float* xr = x + (size_t)row * 1024;
  float4 xv = *(const float4*)(xr + t * 4);
  float v0 = xv.x, v1 = xv.y, v2 = xv.z, v3 = xv.w;
  float s = v0 + v1 + v2 + v3;
  float s2 = v0 * v0 + v1 * v1 + v2 * v2 + v3 * v3;
#pragma unroll
  for (int d = 1; d < 64; d <<= 1) {
    s += __shfl_xor(s, d, 64);
    s2 += __shfl_xor(s2, d, 64);
  }
  __shared__ float red[8];
  int lane = t & 63, wv = t >> 6;
  if (lane == 0) { red[wv] = s; red[4 + wv] = s2; }
  __syncthreads();
  s = red[0] + red[1] + red[2] + red[3];
  s2 = red[4] + red[5] + red[6] + red[7];
  float mu = s * (1.0f / 1024.0f);
  float var = s2 * (1.0f / 1024.0f) - mu * mu;
  float rstd = rsqrtf(var + 1e-5f);
  float4 gv = *(const float4*)(gamma + t * 4);
  float4 bv = *(const float4*)(beta + t * 4);
  u16x4 ov;
  ov.x = f2bf((v0 - mu) * rstd * gv.x + bv.x);
  ov.y = f2bf((v1 - mu) * rstd * gv.y + bv.y);
  ov.z = f2bf((v2 - mu) * rstd * gv.z + bv.z);
  ov.w = f2bf((v3 - mu) * rstd * gv.w + bv.w);
  *(u16x4*)(xn + (size_t)row * 1024 + t * 4) = ov;
}

// ------- GEMM 128x128: C = A(bf16,lda) * BT(bf16)^T ----------------------------
__global__ __launch_bounds__(256) void gemm_bf16_k(const u16* __restrict__ A,
                                                   const u16* __restrict__ BT,
                                                   void* __restrict__ Cp,
                                                   int K, int lda, int ldc,
                                                   int f32out) {
  __shared__ __align__(16) u16 lA[128 * 32];
  __shared__ __align__(16) u16 lB[128 * 32];
  int tid = threadIdx.x;
  int bm = blockIdx.y * 128;
  int bn = blockIdx.x * 128;
  int w = tid >> 6, l = tid & 63;
  int wm = (w >> 1) * 64, wn = (w & 1) * 64;
  int lr = l & 15, lq = l >> 4;
  floatx4 acc[4][4] = {};
  int sr = w * 16 + (l >> 2);
  int sc = (l & 3) * 8;
  for (int k0 = 0; k0 < K; k0 += 32) {
    GL2LDS(A + (size_t)(bm + sr) * lda + k0 + sc, &lA[sr * 32 + sc]);
    GL2LDS(A + (size_t)(bm + sr + 64) * lda + k0 + sc, &lA[(sr + 64) * 32 + sc]);
    GL2LDS(BT + (size_t)(bn + sr) * K + k0 + sc, &lB[sr * 32 + sc]);
    GL2LDS(BT + (size_t)(bn + sr + 64) * K + k0 + sc, &lB[(sr + 64) * 32 + sc]);
    __syncthreads();
    short8 afr[4], bfr[4];
#pragma unroll
    for (int i = 0; i < 4; i++)
      afr[i] = *(const short8*)(&lA[(wm + i * 16 + lr) * 32 + lq * 8]);
#pragma unroll
    for (int i = 0; i < 4; i++)
      bfr[i] = *(const short8*)(&lB[(wn + i * 16 + lr) * 32 + lq * 8]);
#pragma unroll
    for (int mi = 0; mi < 4; mi++)
#pragma unroll
      for (int ni = 0; ni < 4; ni++)
        acc[mi][ni] = __builtin_amdgcn_mfma_f32_16x16x32_bf16(
            afr[mi], bfr[ni], acc[mi][ni], 0, 0, 0);
    __syncthreads();
  }
  if (f32out) {
    float* Cf = (float*)Cp;
#pragma unroll
    for (int mi = 0; mi < 4; mi++)
#pragma unroll
      for (int ni = 0; ni < 4; ni++)
#pragma unroll
        for (int r = 0; r < 4; r++) {
          int row = bm + wm + mi * 16 + lq * 4 + r;
          int col = bn + wn + ni * 16 + lr;
          Cf[(size_t)row * ldc + col] = acc[mi][ni][r];
        }
  } else {
    u16* Cb = (u16*)Cp;
#pragma unroll
    for (int mi = 0; mi < 4; mi++)
#pragma unroll
      for (int ni = 0; ni < 4; ni++)
#pragma unroll
        for (int r = 0; r < 4; r++) {
          int row = bm + wm + mi * 16 + lq * 4 + r;
          int col = bn + wn + ni * 16 + lr;
          Cb[(size_t)row * ldc + col] = f2bf(acc[mi][ni][r]);
        }
  }
}

// ------- GEMM 64x128 (fp32 out): higher block count for small GEMMs ------------
__global__ __launch_bounds__(256) void gemm64_bf16_k(const u16* __restrict__ A,
                                                     const u16* __restrict__ BT,
                                                     float* __restrict__ C,
                                                     int K, int lda, int ldc) {
  __shared__ __align__(16) u16 lA[64 * 32];
  __shared__ __align__(16) u16 lB[128 * 32];
  int tid = threadIdx.x;
  int bm = blockIdx.y * 64;
  int bn = blockIdx.x * 128;
  int w = tid >> 6, l = tid & 63;
  int wm = (w >> 1) * 32, wn = (w & 1) * 64;
  int lr = l & 15, lq = l >> 4;
  floatx4 acc[2][4] = {};
  int sr = w * 16 + (l >> 2);
  int sc = (l & 3) * 8;
  for (int k0 = 0; k0 < K; k0 += 32) {
    GL2LDS(A + (size_t)(bm + sr) * lda + k0 + sc, &lA[sr * 32 + sc]);
    GL2LDS(BT + (size_t)(bn + sr) * K + k0 + sc, &lB[sr * 32 + sc]);
    GL2LDS(BT + (size_t)(bn + sr + 64) * K + k0 + sc, &lB[(sr + 64) * 32 + sc]);
    __syncthreads();
    short8 afr[2], bfr[4];
#pragma unroll
    for (int i = 0; i < 2; i++)
      afr[i] = *(const short8*)(&lA[(wm + i * 16 + lr) * 32 + lq * 8]);
#pragma unroll
    for (int i = 0; i < 4; i++)
      bfr[i] = *(const short8*)(&lB[(wn + i * 16 + lr) * 32 + lq * 8]);
#pragma unroll
    for (int mi = 0; mi < 2; mi++)
#pragma unroll
      for (int ni = 0; ni < 4; ni++)
        acc[mi][ni] = __builtin_amdgcn_mfma_f32_16x16x32_bf16(
            afr[mi], bfr[ni], acc[mi][ni], 0, 0, 0);
    __syncthreads();
  }
#pragma unroll
  for (int mi = 0; mi < 2; mi++)
#pragma unroll
    for (int ni = 0; ni < 4; ni++)
#pragma unroll
      for (int r = 0; r < 4; r++) {
        int row = bm + wm + mi * 16 + lq * 4 + r;
        int col = bn + wn + ni * 16 + lr;
        C[(size_t)row * ldc + col] = acc[mi][ni][r];
      }
}

// ------- RoPE (in-place, vectorized) + q scale (x 0.125 x log2e) ---------------
__global__ __launch_bounds__(256) void rope_inplace_k(u16* __restrict__ qkv) {
  int idx = blockIdx.x * 256 + threadIdx.x;
  int ig = idx & 7;
  int h = (idx >> 3) & 15;
  int row = idx >> 7;
  int n = row & 2047;
  int i0 = ig * 4;
  const float QS = 0.125f * 1.44269504088896f;
  float c_[4], s_[4];
  float invf = exp2f(-(float)i0 * 0.4152410118609203f);
  const float rstep = 0.74989420933245582f;
#pragma unroll
  for (int e = 0; e < 4; e++) {
    float ang = (float)n * invf;
    c_[e] = cosf(ang);
    s_[e] = sinf(ang);
    invf *= rstep;
  }
  size_t base = (size_t)row * 3072 + h * 64 + i0;
  u16x4 qlo = *(u16x4*)(qkv + base);
  u16x4 qhi = *(u16x4*)(qkv + base + 32);
  u16x4 klo = *(u16x4*)(qkv + base + 1024);
  u16x4 khi = *(u16x4*)(qkv + base + 1056);
  u16x4 oqlo, oqhi, oklo, okhi;
#pragma unroll
  for (int e = 0; e < 4; e++) {
    float x1 = bf2f(((u16*)&qlo)[e]), x2 = bf2f(((u16*)&qhi)[e]);
    ((u16*)&oqlo)[e] = f2bf((x1 * c_[e] - x2 * s_[e]) * QS);
    ((u16*)&oqhi)[e] = f2bf((x2 * c_[e] + x1 * s_[e]) * QS);
    x1 = bf2f(((u16*)&klo)[e]); x2 = bf2f(((u16*)&khi)[e]);
    ((u16*)&oklo)[e] = f2bf(x1 * c_[e] - x2 * s_[e]);
    ((u16*)&okhi)[e] = f2bf(x2 * c_[e] + x1 * s_[e]);
  }
  *(u16x4*)(qkv + base) = oqlo;
  *(u16x4*)(qkv + base + 32) = oqhi;
  *(u16x4*)(qkv + base + 1024) = oklo;
  *(u16x4*)(qkv + base + 1056) = okhi;
}

// ------- V transpose: qkv v-slice (n,64) -> vT (bh, 64, n), bf16 ---------------
__global__ __launch_bounds__(256) void transpose_v_k(const u16* __restrict__ qkv,
                                                     u16* __restrict__ vT) {
  __shared__ u16 tile[32][33];
  int bh = blockIdx.z;
  int b = bh >> 4, h = bh & 15;
  int n0 = blockIdx.x * 32, d0 = blockIdx.y * 32;
  int tx = threadIdx.x, ty = threadIdx.y;
#pragma unroll
  for (int i = 0; i < 32; i += 8)
    tile[ty + i][tx] =
        qkv[(size_t)(b * 2048 + n0 + ty + i) * 3072 + 2048 + h * 64 + d0 + tx];
  __syncthreads();
#pragma unroll
  for (int i = 0; i < 32; i += 8)
    vT[((size_t)bh * 64 + d0 + ty + i) * 2048 + n0 + tx] = tile[tx][ty + i];
}

// ------- flash attention (causal), S^T formulation, exp2 domain ----------------
// 512 blocks x 256 thr; block p pairs q-tiles p and 31-p (64 rows each; wave w
// owns 16 rows of each). K/V staged via GL2LDS into XOR-swizzled LDS.
// S^T = K.Q^T: lane holds q-col = lane&15, 16 key-rows -> m/l scalars per lane,
// 2-step shuffle max, row-sum via ones-MFMA over stored bf16 P (consistent).
#define LPT 72
__device__ __forceinline__ void attn_tile2(const u16* lK, const u16* lV, u16* lp,
                                           const short8* aq, floatx4* o,
                                           float& m_i, float& l_i, int lr, int lq,
                                           bool diag, int q0, int k0g,
                                           short8 ones) {
  floatx4 s[4];
#pragma unroll
  for (int ni = 0; ni < 4; ni++) {
    floatx4 a = {};
#pragma unroll
    for (int kc = 0; kc < 2; kc++) {
      int R = ni * 16 + lr;
      int c8 = (kc * 4 + lq) ^ (R & 7);
      short8 kf = *(const short8*)&lK[R * 64 + c8 * 8];
      a = __builtin_amdgcn_mfma_f32_16x16x32_bf16(kf, aq[kc], a, 0, 0, 0);
    }
    s[ni] = a;
  }
  if (diag) {
    int qg = q0 + lr;
#pragma unroll
    for (int ni = 0; ni < 4; ni++)
#pragma unroll
      for (int r = 0; r < 4; r++) {
        int kg = k0g + ni * 16 + lq * 4 + r;
        if (kg > qg) s[ni][r] = -1e30f;
      }
  }
  // max over 16 in-lane + 2 shuffle steps (lanes ^16, ^32 share q-col)
  float mx = fmaxf(fmaxf(s[0][0], s[0][1]), fmaxf(s[0][2], s[0][3]));
#pragma unroll
  for (int ni = 1; ni < 4; ni++)
    mx = fmaxf(mx, fmaxf(fmaxf(s[ni][0], s[ni][1]), fmaxf(s[ni][2], s[ni][3])));
  mx = fmaxf(mx, __shfl_xor(mx, 16, 64));
  mx = fmaxf(mx, __shfl_xor(mx, 32, 64));
  float mnew = fmaxf(m_i, mx);
  float alpha = exp2f(m_i - mnew);
  m_i = mnew;
  // P^T -> lp[q=lr][key] as truncated bf16, packed 8B writes
#pragma unroll
  for (int ni = 0; ni < 4; ni++) {
    float p0 = exp2f(s[ni][0] - mnew), p1 = exp2f(s[ni][1] - mnew);
    float p2 = exp2f(s[ni][2] - mnew), p3 = exp2f(s[ni][3] - mnew);
    uint2v dw;
    dw.x = (fu(p0) >> 16) | (fu(p1) & 0xFFFF0000u);
    dw.y = (fu(p2) >> 16) | (fu(p3) & 0xFFFF0000u);
    *(uint2v*)&lp[lr * LPT + ni * 16 + lq * 4] = dw;
  }
  short8 pb0 = *(const short8*)&lp[lr * LPT + lq * 8];
  short8 pb1 = *(const short8*)&lp[lr * LPT + 32 + lq * 8];
  // row-sum via ones-MFMA (sums the stored bf16 P exactly)
  floatx4 z = {};
  z = __builtin_amdgcn_mfma_f32_16x16x32_bf16(ones, pb0, z, 0, 0, 0);
  z = __builtin_amdgcn_mfma_f32_16x16x32_bf16(ones, pb1, z, 0, 0, 0);
  l_i = l_i * alpha + z[0];
#pragma unroll
  for (int di = 0; di < 4; di++)
#pragma unroll
    for (int r = 0; r < 4; r++) o[di][r] *= alpha;
  // O^T += V^T.P^T
#pragma unroll
  for (int di = 0; di < 4; di++) {
    int R = di * 16 + lr;
    int c80 = lq ^ (R & 7);
    int c81 = (4 + lq) ^ (R & 7);
    short8 v0 = *(const short8*)&lV[R * 64 + c80 * 8];
    o[di] = __builtin_amdgcn_mfma_f32_16x16x32_bf16(v0, pb0, o[di], 0, 0, 0);
    short8 v1 = *(const short8*)&lV[R * 64 + c81 * 8];
    o[di] = __builtin_amdgcn_mfma_f32_16x16x32_bf16(v1, pb1, o[di], 0, 0, 0);
  }
}

__global__ __launch_bounds__(256) void attn_k(const u16* __restrict__ qkv,
                                              const u16* __restrict__ vt,
                                              u16* __restrict__ out) {
  __shared__ __align__(16) u16 lK[64 * 64];
  __shared__ __align__(16) u16 lV[64 * 64];
  __shared__ __align__(16) u16 lP[4][16 * LPT];
  int bh = blockIdx.y;
  int b = bh >> 4, h = bh & 15;
  int p = blockIdx.x;
  int jB = 31 - p;
  int tid = threadIdx.x;
  int w = tid >> 6, l = tid & 63;
  int lr = l & 15, lq = l >> 4;
  int q0A = p * 64 + w * 16;
  int q0B = jB * 64 + w * 16;
  const u16* qb = qkv + (size_t)b * 2048 * 3072 + h * 64;
  const u16* kb = qkv + (size_t)b * 2048 * 3072 + 1024 + h * 64;
  const u16* vb = vt + (size_t)bh * 64 * 2048;
  short8 aqA[2], aqB[2];  // Q as B-fragments: B[k=lq*8+j][n=lr]
  aqA[0] = *(const short8*)(qb + (size_t)(q0A + lr) * 3072 + lq * 8);
  aqA[1] = *(const short8*)(qb + (size_t)(q0A + lr) * 3072 + 32 + lq * 8);
  aqB[0] = *(const short8*)(qb + (size_t)(q0B + lr) * 3072 + lq * 8);
  aqB[1] = *(const short8*)(qb + (size_t)(q0B + lr) * 3072 + 32 + lq * 8);
  short8 ones;
#pragma unroll
  for (int i = 0; i < 8; i++) ones[i] = (short)0x3F80;  // bf16 1.0
  floatx4 oA[4] = {}, oB[4] = {};
  float mA = -1e30f, lA_ = 0.0f, mB = -1e30f, lB_ = 0.0f;
  int srow8 = l >> 3;
  int sc8 = (l & 7) ^ srow8;  // source col8 swizzle: phys = logical ^ (row&7)
  u16* lp = &lP[w][0];
  for (int kt = 0; kt <= jB; ++kt) {
#pragma unroll
    for (int c = 0; c < 2; c++) {
      int m = w + c * 4;  // 8-row chunk
      int row = m * 8 + srow8;
      GL2LDS(kb + (size_t)(kt * 64 + row) * 3072 + sc8 * 8, &lK[m * 512]);
      GL2LDS(vb + (size_t)row * 2048 + kt * 64 + sc8 * 8, &lV[m * 512]);
    }
    __syncthreads();
    attn_tile2(lK, lV, lp, aqB, oB, mB, lB_, lr, lq, kt == jB, q0B, kt * 64, ones);
    if (kt <= p)
      attn_tile2(lK, lV, lp, aqA, oA, mA, lA_, lr, lq, kt == p, q0A, kt * 64, ones);
    __syncthreads();
  }
  float rlA = 1.0f / lA_, rlB = 1.0f / lB_;
#pragma unroll
  for (int di = 0; di < 4; di++) {
    uint2v dwA, dwB;
    u16 a0 = f2bf(oA[di][0] * rlA), a1 = f2bf(oA[di][1] * rlA);
    u16 a2 = f2bf(oA[di][2] * rlA), a3 = f2bf(oA[di][3] * rlA);
    dwA.x = (uint32_t)a0 | ((uint32_t)a1 << 16);
    dwA.y = (uint32_t)a2 | ((uint32_t)a3 << 16);
    u16 b0 = f2bf(oB[di][0] * rlB), b1 = f2bf(oB[di][1] * rlB);
    u16 b2 = f2bf(oB[di][2] * rlB), b3 = f2bf(oB[di][3] * rlB);
    dwB.x = (uint32_t)b0 | ((uint32_t)b1 << 16);
    dwB.y = (uint32_t)b2 | ((uint32_t)b3 << 16);
    int dcol = h * 64 + di * 16 + lq * 4;
    *(uint2v*)(out + ((size_t)(b * 2048 + q0A + lr)) * 3072 + dcol) = dwA;
    *(uint2v*)(out + ((size_t)(b * 2048 + q0B + lr)) * 3072 + dcol) = dwB;
  }
}

// ------- launch ---------------------------------------------------------------
extern "C" void kernel_launch(void* const* d_in, const int* in_sizes, int n_in,
                              void* d_out, int out_size, void* d_ws, size_t ws_size,
                              hipStream_t stream) {
  const float* x = (const float*)d_in[0];
  const float* gamma = (const float*)d_in[1];
  const float* beta = (const float*)d_in[2];
  const float* Wq = (const float*)d_in[3];
  const float* Wkv = (const float*)d_in[4];
  const float* Wo = (const float*)d_in[5];
  float* out = (float*)d_out;
  char* ws = (char*)d_ws;

  u16* qkv = (u16*)(ws);               // 4096x3072 bf16 = 24 MiB
  u16* wqkvT = (u16*)(ws + 25165824);  // 3072x1024 = 6 MiB
  u16* woT = (u16*)(ws + 31457280);    // 1024x1024 = 2 MiB
  u16* xn = (u16*)(ws + 33554432);     // 4096x1024 = 8 MiB
  u16* vT = xn;                        // alias: xn dead after GEMM1
  u16* attn_out = qkv + 2048;          // v-slice of qkv (dead after transpose_v)

  dim3 tb32(32, 8);
  transpose_w_k<<<dim3(32, 32), tb32, 0, stream>>>(Wq, wqkvT, 1024, 1024);
  transpose_w_k<<<dim3(64, 32), tb32, 0, stream>>>(Wkv, wqkvT + 1024 * 1024, 1024, 2048);
  transpose_w_k<<<dim3(32, 32), tb32, 0, stream>>>(Wo, woT, 1024, 1024);
  layernorm_k<<<4096, 256, 0, stream>>>(x, gamma, beta, xn);
  gemm_bf16_k<<<dim3(24, 32), 256, 0, stream>>>(xn, wqkvT, qkv, 1024, 1024, 3072, 0);
  rope_inplace_k<<<2048, 256, 0, stream>>>(qkv);
  transpose_v_k<<<dim3(64, 2, 32), tb32, 0, stream>>>(qkv, vT);
  attn_k<<<dim3(16, 32), 256, 0, stream>>>(qkv, vT, attn_out);
  gemm64_bf16_k<<<dim3(8, 64), 256, 0, stream>>>(attn_out, woT, out, 1024, 3072, 1024);
}

// Round 7
// 214.313 us; speedup vs baseline: 1.1657x; 1.0175x over previous
//
#include <hip/hip_runtime.h>
#include <stdint.h>

typedef unsigned short u16;
typedef __attribute__((ext_vector_type(8))) short short8;
typedef __attribute__((ext_vector_type(4))) float floatx4;
typedef __attribute__((ext_vector_type(4))) unsigned short u16x4;
typedef __attribute__((ext_vector_type(2))) unsigned int uint2v;

__device__ __forceinline__ float bf2f(u16 v) {
  union { uint32_t u; float f; } x; x.u = ((uint32_t)v) << 16; return x.f;
}
__device__ __forceinline__ u16 f2bf(float f) {
  union { float f; uint32_t u; } x; x.f = f;
  uint32_t r = x.u + 0x7fffu + ((x.u >> 16) & 1u);
  return (u16)(r >> 16);
}
__device__ __forceinline__ uint32_t fu(float f) {
  union { float f; uint32_t u; } x; x.f = f; return x.u;
}

#define GL2LDS(g, l)                                                          \
  __builtin_amdgcn_global_load_lds(                                           \
      (const __attribute__((address_space(1))) void*)(g),                     \
      (__attribute__((address_space(3))) void*)(l), 16, 0, 0)

// ------- merged weight transposes: fp32 (R x C) -> bf16 (C x R), 3 mats --------
__global__ __launch_bounds__(256) void transpose_w3_k(const float* __restrict__ Wq,
                                                      const float* __restrict__ Wkv,
                                                      const float* __restrict__ Wo,
                                                      u16* __restrict__ wqkvT,
                                                      u16* __restrict__ woT) {
  __shared__ float tile[32][33];
  int z = blockIdx.z;
  const float* in = (z == 0) ? Wq : (z == 1) ? Wkv : Wo;
  u16* out = (z == 0) ? wqkvT : (z == 1) ? (wqkvT + 1024 * 1024) : woT;
  int C = (z == 1) ? 2048 : 1024;
  int c0 = blockIdx.x * 32, r0 = blockIdx.y * 32;
  if (c0 >= C) return;
  int tx = threadIdx.x, ty = threadIdx.y;
#pragma unroll
  for (int i = 0; i < 32; i += 8)
    tile[ty + i][tx] = in[(size_t)(r0 + ty + i) * C + c0 + tx];
  __syncthreads();
#pragma unroll
  for (int i = 0; i < 32; i += 8)
    out[(size_t)(c0 + ty + i) * 1024 + r0 + tx] = f2bf(tile[tx][ty + i]);
}

// ------- layernorm: 4096 rows x 1024, fp32 in -> bf16 out ----------------------
__global__ __launch_bounds__(256) void layernorm_k(const float* __restrict__ x,
                                                   const float* __restrict__ gamma,
                                                   const float* __restrict__ beta,
                                                   u16* __restrict__ xn) {
  int row = blockIdx.x;
  int t = threadIdx.x;
  const float* xr = x + (size_t)row * 1024;
  float4 xv = *(const float4*)(xr + t * 4);
  float v0 = xv.x, v1 = xv.y, v2 = xv.z, v3 = xv.w;
  float s = v0 + v1 + v2 + v3;
  float s2 = v0 * v0 + v1 * v1 + v2 * v2 + v3 * v3;
#pragma unroll
  for (int d = 1; d < 64; d <<= 1) {
    s += __shfl_xor(s, d, 64);
    s2 += __shfl_xor(s2, d, 64);
  }
  __shared__ float red[8];
  int lane = t & 63, wv = t >> 6;
  if (lane == 0) { red[wv] = s; red[4 + wv] = s2; }
  __syncthreads();
  s = red[0] + red[1] + red[2] + red[3];
  s2 = red[4] + red[5] + red[6] + red[7];
  float mu = s * (1.0f / 1024.0f);
  float var = s2 * (1.0f / 1024.0f) - mu * mu;
  float rstd = rsqrtf(var + 1e-5f);
  float4 gv = *(const float4*)(gamma + t * 4);
  float4 bv = *(const float4*)(beta + t * 4);
  u16x4 ov;
  ov.x = f2bf((v0 - mu) * rstd * gv.x + bv.x);
  ov.y = f2bf((v1 - mu) * rstd * gv.y + bv.y);
  ov.z = f2bf((v2 - mu) * rstd * gv.z + bv.z);
  ov.w = f2bf((v3 - mu) * rstd * gv.w + bv.w);
  *(u16x4*)(xn + (size_t)row * 1024 + t * 4) = ov;
}

// ------- GEMM 128x128: C = A(bf16,lda) * BT(bf16)^T ----------------------------
__global__ __launch_bounds__(256) void gemm_bf16_k(const u16* __restrict__ A,
                                                   const u16* __restrict__ BT,
                                                   void* __restrict__ Cp,
                                                   int K, int lda, int ldc,
                                                   int f32out) {
  __shared__ __align__(16) u16 lA[128 * 32];
  __shared__ __align__(16) u16 lB[128 * 32];
  int tid = threadIdx.x;
  int bm = blockIdx.y * 128;
  int bn = blockIdx.x * 128;
  int w = tid >> 6, l = tid & 63;
  int wm = (w >> 1) * 64, wn = (w & 1) * 64;
  int lr = l & 15, lq = l >> 4;
  floatx4 acc[4][4] = {};
  int sr = w * 16 + (l >> 2);
  int sc = (l & 3) * 8;
  for (int k0 = 0; k0 < K; k0 += 32) {
    GL2LDS(A + (size_t)(bm + sr) * lda + k0 + sc, &lA[sr * 32 + sc]);
    GL2LDS(A + (size_t)(bm + sr + 64) * lda + k0 + sc, &lA[(sr + 64) * 32 + sc]);
    GL2LDS(BT + (size_t)(bn + sr) * K + k0 + sc, &lB[sr * 32 + sc]);
    GL2LDS(BT + (size_t)(bn + sr + 64) * K + k0 + sc, &lB[(sr + 64) * 32 + sc]);
    __syncthreads();
    short8 afr[4], bfr[4];
#pragma unroll
    for (int i = 0; i < 4; i++)
      afr[i] = *(const short8*)(&lA[(wm + i * 16 + lr) * 32 + lq * 8]);
#pragma unroll
    for (int i = 0; i < 4; i++)
      bfr[i] = *(const short8*)(&lB[(wn + i * 16 + lr) * 32 + lq * 8]);
#pragma unroll
    for (int mi = 0; mi < 4; mi++)
#pragma unroll
      for (int ni = 0; ni < 4; ni++)
        acc[mi][ni] = __builtin_amdgcn_mfma_f32_16x16x32_bf16(
            afr[mi], bfr[ni], acc[mi][ni], 0, 0, 0);
    __syncthreads();
  }
  if (f32out) {
    float* Cf = (float*)Cp;
#pragma unroll
    for (int mi = 0; mi < 4; mi++)
#pragma unroll
      for (int ni = 0; ni < 4; ni++)
#pragma unroll
        for (int r = 0; r < 4; r++) {
          int row = bm + wm + mi * 16 + lq * 4 + r;
          int col = bn + wn + ni * 16 + lr;
          Cf[(size_t)row * ldc + col] = acc[mi][ni][r];
        }
  } else {
    u16* Cb = (u16*)Cp;
#pragma unroll
    for (int mi = 0; mi < 4; mi++)
#pragma unroll
      for (int ni = 0; ni < 4; ni++)
#pragma unroll
        for (int r = 0; r < 4; r++) {
          int row = bm + wm + mi * 16 + lq * 4 + r;
          int col = bn + wn + ni * 16 + lr;
          Cb[(size_t)row * ldc + col] = f2bf(acc[mi][ni][r]);
        }
  }
}

// ------- GEMM 64x128 (fp32 out): higher block count for small GEMMs ------------
__global__ __launch_bounds__(256) void gemm64_bf16_k(const u16* __restrict__ A,
                                                     const u16* __restrict__ BT,
                                                     float* __restrict__ C,
                                                     int K, int lda, int ldc) {
  __shared__ __align__(16) u16 lA[64 * 32];
  __shared__ __align__(16) u16 lB[128 * 32];
  int tid = threadIdx.x;
  int bm = blockIdx.y * 64;
  int bn = blockIdx.x * 128;
  int w = tid >> 6, l = tid & 63;
  int wm = (w >> 1) * 32, wn = (w & 1) * 64;
  int lr = l & 15, lq = l >> 4;
  floatx4 acc[2][4] = {};
  int sr = w * 16 + (l >> 2);
  int sc = (l & 3) * 8;
  for (int k0 = 0; k0 < K; k0 += 32) {
    GL2LDS(A + (size_t)(bm + sr) * lda + k0 + sc, &lA[sr * 32 + sc]);
    GL2LDS(BT + (size_t)(bn + sr) * K + k0 + sc, &lB[sr * 32 + sc]);
    GL2LDS(BT + (size_t)(bn + sr + 64) * K + k0 + sc, &lB[(sr + 64) * 32 + sc]);
    __syncthreads();
    short8 afr[2], bfr[4];
#pragma unroll
    for (int i = 0; i < 2; i++)
      afr[i] = *(const short8*)(&lA[(wm + i * 16 + lr) * 32 + lq * 8]);
#pragma unroll
    for (int i = 0; i < 4; i++)
      bfr[i] = *(const short8*)(&lB[(wn + i * 16 + lr) * 32 + lq * 8]);
#pragma unroll
    for (int mi = 0; mi < 2; mi++)
#pragma unroll
      for (int ni = 0; ni < 4; ni++)
        acc[mi][ni] = __builtin_amdgcn_mfma_f32_16x16x32_bf16(
            afr[mi], bfr[ni], acc[mi][ni], 0, 0, 0);
    __syncthreads();
  }
#pragma unroll
  for (int mi = 0; mi < 2; mi++)
#pragma unroll
    for (int ni = 0; ni < 4; ni++)
#pragma unroll
      for (int r = 0; r < 4; r++) {
        int row = bm + wm + mi * 16 + lq * 4 + r;
        int col = bn + wn + ni * 16 + lr;
        C[(size_t)row * ldc + col] = acc[mi][ni][r];
      }
}

// ------- RoPE (in-place, vectorized) + q scale (x 0.125 x log2e) ---------------
__global__ __launch_bounds__(256) void rope_inplace_k(u16* __restrict__ qkv) {
  int idx = blockIdx.x * 256 + threadIdx.x;
  int ig = idx & 7;
  int h = (idx >> 3) & 15;
  int row = idx >> 7;
  int n = row & 2047;
  int i0 = ig * 4;
  const float QS = 0.125f * 1.44269504088896f;
  float c_[4], s_[4];
  float invf = exp2f(-(float)i0 * 0.4152410118609203f);
  const float rstep = 0.74989420933245582f;
#pragma unroll
  for (int e = 0; e < 4; e++) {
    float ang = (float)n * invf;
    c_[e] = cosf(ang);
    s_[e] = sinf(ang);
    invf *= rstep;
  }
  size_t base = (size_t)row * 3072 + h * 64 + i0;
  u16x4 qlo = *(u16x4*)(qkv + base);
  u16x4 qhi = *(u16x4*)(qkv + base + 32);
  u16x4 klo = *(u16x4*)(qkv + base + 1024);
  u16x4 khi = *(u16x4*)(qkv + base + 1056);
  u16x4 oqlo, oqhi, oklo, okhi;
#pragma unroll
  for (int e = 0; e < 4; e++) {
    float x1 = bf2f(((u16*)&qlo)[e]), x2 = bf2f(((u16*)&qhi)[e]);
    ((u16*)&oqlo)[e] = f2bf((x1 * c_[e] - x2 * s_[e]) * QS);
    ((u16*)&oqhi)[e] = f2bf((x2 * c_[e] + x1 * s_[e]) * QS);
    x1 = bf2f(((u16*)&klo)[e]); x2 = bf2f(((u16*)&khi)[e]);
    ((u16*)&oklo)[e] = f2bf(x1 * c_[e] - x2 * s_[e]);
    ((u16*)&okhi)[e] = f2bf(x2 * c_[e] + x1 * s_[e]);
  }
  *(u16x4*)(qkv + base) = oqlo;
  *(u16x4*)(qkv + base + 32) = oqhi;
  *(u16x4*)(qkv + base + 1024) = oklo;
  *(u16x4*)(qkv + base + 1056) = okhi;
}

// ------- V transpose: qkv v-slice (n,64) -> vT (bh, 64, n), bf16 ---------------
__global__ __launch_bounds__(256) void transpose_v_k(const u16* __restrict__ qkv,
                                                     u16* __restrict__ vT) {
  __shared__ u16 tile[32][33];
  int bh = blockIdx.z;
  int b = bh >> 4, h = bh & 15;
  int n0 = blockIdx.x * 32, d0 = blockIdx.y * 32;
  int tx = threadIdx.x, ty = threadIdx.y;
#pragma unroll
  for (int i = 0; i < 32; i += 8)
    tile[ty + i][tx] =
        qkv[(size_t)(b * 2048 + n0 + ty + i) * 3072 + 2048 + h * 64 + d0 + tx];
  __syncthreads();
#pragma unroll
  for (int i = 0; i < 32; i += 8)
    vT[((size_t)bh * 64 + d0 + ty + i) * 2048 + n0 + tx] = tile[tx][ty + i];
}

// ------- flash attention (causal), S^T formulation, exp2 domain ----------------
// 512 blocks x 256 thr; block p pairs q-tiles p and 31-p. Double-buffered K/V:
// prefetch tile kt+1 issued AFTER the barrier that publishes tile kt, so the
// GL2LDS stays in flight across compute and is drained by the NEXT barrier.
#define LPT 72
__device__ __forceinline__ void attn_tile2(const u16* lK, const u16* lV, u16* lp,
                                           const short8* aq, floatx4* o,
                                           float& m_i, float& l_i, int lr, int lq,
                                           bool diag, int q0, int k0g,
                                           short8 ones) {
  floatx4 s[4];
#pragma unroll
  for (int ni = 0; ni < 4; ni++) {
    floatx4 a = {};
#pragma unroll
    for (int kc = 0; kc < 2; kc++) {
      int R = ni * 16 + lr;
      int c8 = (kc * 4 + lq) ^ (R & 7);
      short8 kf = *(const short8*)&lK[R * 64 + c8 * 8];
      a = __builtin_amdgcn_mfma_f32_16x16x32_bf16(kf, aq[kc], a, 0, 0, 0);
    }
    s[ni] = a;
  }
  if (diag) {
    int qg = q0 + lr;
#pragma unroll
    for (int ni = 0; ni < 4; ni++)
#pragma unroll
      for (int r = 0; r < 4; r++) {
        int kg = k0g + ni * 16 + lq * 4 + r;
        if (kg > qg) s[ni][r] = -1e30f;
      }
  }
  float mx = fmaxf(fmaxf(s[0][0], s[0][1]), fmaxf(s[0][2], s[0][3]));
#pragma unroll
  for (int ni = 1; ni < 4; ni++)
    mx = fmaxf(mx, fmaxf(fmaxf(s[ni][0], s[ni][1]), fmaxf(s[ni][2], s[ni][3])));
  mx = fmaxf(mx, __shfl_xor(mx, 16, 64));
  mx = fmaxf(mx, __shfl_xor(mx, 32, 64));
  float mnew = fmaxf(m_i, mx);
  float alpha = exp2f(m_i - mnew);
  m_i = mnew;
  // P^T -> lp[q=lr][key], truncated bf16, packed via v_perm (1 op/pair)
#pragma unroll
  for (int ni = 0; ni < 4; ni++) {
    float p0 = exp2f(s[ni][0] - mnew), p1 = exp2f(s[ni][1] - mnew);
    float p2 = exp2f(s[ni][2] - mnew), p3 = exp2f(s[ni][3] - mnew);
    uint2v dw;
    dw.x = __builtin_amdgcn_perm(fu(p1), fu(p0), 0x07060302u);
    dw.y = __builtin_amdgcn_perm(fu(p3), fu(p2), 0x07060302u);
    *(uint2v*)&lp[lr * LPT + ni * 16 + lq * 4] = dw;
  }
  short8 pb0 = *(const short8*)&lp[lr * LPT + lq * 8];
  short8 pb1 = *(const short8*)&lp[lr * LPT + 32 + lq * 8];
  floatx4 z = {};
  z = __builtin_amdgcn_mfma_f32_16x16x32_bf16(ones, pb0, z, 0, 0, 0);
  z = __builtin_amdgcn_mfma_f32_16x16x32_bf16(ones, pb1, z, 0, 0, 0);
  l_i = l_i * alpha + z[0];
#pragma unroll
  for (int di = 0; di < 4; di++)
#pragma unroll
    for (int r = 0; r < 4; r++) o[di][r] *= alpha;
#pragma unroll
  for (int di = 0; di < 4; di++) {
    int R = di * 16 + lr;
    int c80 = lq ^ (R & 7);
    int c81 = (4 + lq) ^ (R & 7);
    short8 v0 = *(const short8*)&lV[R * 64 + c80 * 8];
    o[di] = __builtin_amdgcn_mfma_f32_16x16x32_bf16(v0, pb0, o[di], 0, 0, 0);
    short8 v1 = *(const short8*)&lV[R * 64 + c81 * 8];
    o[di] = __builtin_amdgcn_mfma_f32_16x16x32_bf16(v1, pb1, o[di], 0, 0, 0);
  }
}

__global__ __launch_bounds__(256) void attn_k(const u16* __restrict__ qkv,
                                              const u16* __restrict__ vt,
                                              u16* __restrict__ out) {
  __shared__ __align__(16) u16 lK[2][64 * 64];
  __shared__ __align__(16) u16 lV[2][64 * 64];
  __shared__ __align__(16) u16 lP[4][16 * LPT];
  int bh = blockIdx.y;
  int b = bh >> 4, h = bh & 15;
  int p = blockIdx.x;
  int jB = 31 - p;
  int tid = threadIdx.x;
  int w = tid >> 6, l = tid & 63;
  int lr = l & 15, lq = l >> 4;
  int q0A = p * 64 + w * 16;
  int q0B = jB * 64 + w * 16;
  const u16* qb = qkv + (size_t)b * 2048 * 3072 + h * 64;
  const u16* kb = qkv + (size_t)b * 2048 * 3072 + 1024 + h * 64;
  const u16* vb = vt + (size_t)bh * 64 * 2048;
  short8 aqA[2], aqB[2];
  aqA[0] = *(const short8*)(qb + (size_t)(q0A + lr) * 3072 + lq * 8);
  aqA[1] = *(const short8*)(qb + (size_t)(q0A + lr) * 3072 + 32 + lq * 8);
  aqB[0] = *(const short8*)(qb + (size_t)(q0B + lr) * 3072 + lq * 8);
  aqB[1] = *(const short8*)(qb + (size_t)(q0B + lr) * 3072 + 32 + lq * 8);
  short8 ones;
#pragma unroll
  for (int i = 0; i < 8; i++) ones[i] = (short)0x3F80;
  floatx4 oA[4] = {}, oB[4] = {};
  float mA = -1e30f, lA_ = 0.0f, mB = -1e30f, lB_ = 0.0f;
  int srow8 = l >> 3;
  int sc8 = (l & 7) ^ srow8;
  u16* lp = &lP[w][0];
  auto stage = [&](int bufi, int kt) {
#pragma unroll
    for (int c = 0; c < 2; c++) {
      int m = w + c * 4;
      int row = m * 8 + srow8;
      GL2LDS(kb + (size_t)(kt * 64 + row) * 3072 + sc8 * 8, &lK[bufi][m * 512]);
      GL2LDS(vb + (size_t)row * 2048 + kt * 64 + sc8 * 8, &lV[bufi][m * 512]);
    }
  };
  stage(0, 0);
  for (int kt = 0; kt <= jB; ++kt) {
    int cur = kt & 1;
    __syncthreads();  // publishes buf[cur] (drains its GL2LDS), guards buf reuse
    if (kt < jB) stage(cur ^ 1, kt + 1);  // in flight during compute below
    attn_tile2(lK[cur], lV[cur], lp, aqB, oB, mB, lB_, lr, lq, kt == jB, q0B,
               kt * 64, ones);
    if (kt <= p)
      attn_tile2(lK[cur], lV[cur], lp, aqA, oA, mA, lA_, lr, lq, kt == p, q0A,
                 kt * 64, ones);
  }
  float rlA = 1.0f / lA_, rlB = 1.0f / lB_;
#pragma unroll
  for (int di = 0; di < 4; di++) {
    uint2v dwA, dwB;
    u16 a0 = f2bf(oA[di][0] * rlA), a1 = f2bf(oA[di][1] * rlA);
    u16 a2 = f2bf(oA[di][2] * rlA), a3 = f2bf(oA[di][3] * rlA);
    dwA.x = (uint32_t)a0 | ((uint32_t)a1 << 16);
    dwA.y = (uint32_t)a2 | ((uint32_t)a3 << 16);
    u16 b0 = f2bf(oB[di][0] * rlB), b1 = f2bf(oB[di][1] * rlB);
    u16 b2 = f2bf(oB[di][2] * rlB), b3 = f2bf(oB[di][3] * rlB);
    dwB.x = (uint32_t)b0 | ((uint32_t)b1 << 16);
    dwB.y = (uint32_t)b2 | ((uint32_t)b3 << 16);
    int dcol = h * 64 + di * 16 + lq * 4;
    *(uint2v*)(out + ((size_t)(b * 2048 + q0A + lr)) * 3072 + dcol) = dwA;
    *(uint2v*)(out + ((size_t)(b * 2048 + q0B + lr)) * 3072 + dcol) = dwB;
  }
}

// ------- launch ---------------------------------------------------------------
extern "C" void kernel_launch(void* const* d_in, const int* in_sizes, int n_in,
                              void* d_out, int out_size, void* d_ws, size_t ws_size,
                              hipStream_t stream) {
  const float* x = (const float*)d_in[0];
  const float* gamma = (const float*)d_in[1];
  const float* beta = (const float*)d_in[2];
  const float* Wq = (const float*)d_in[3];
  const float* Wkv = (const float*)d_in[4];
  const float* Wo = (const float*)d_in[5];
  float* out = (float*)d_out;
  char* ws = (char*)d_ws;

  u16* qkv = (u16*)(ws);               // 4096x3072 bf16 = 24 MiB
  u16* wqkvT = (u16*)(ws + 25165824);  // 3072x1024 = 6 MiB
  u16* woT = (u16*)(ws + 31457280);    // 1024x1024 = 2 MiB
  u16* xn = (u16*)(ws + 33554432);     // 4096x1024 = 8 MiB
  u16* vT = xn;                        // alias: xn dead after GEMM1
  u16* attn_out = qkv + 2048;          // v-slice of qkv (dead after transpose_v)

  dim3 tb32(32, 8);
  transpose_w3_k<<<dim3(64, 32, 3), tb32, 0, stream>>>(Wq, Wkv, Wo, wqkvT, woT);
  layernorm_k<<<4096, 256, 0, stream>>>(x, gamma, beta, xn);
  gemm_bf16_k<<<dim3(24, 32), 256, 0, stream>>>(xn, wqkvT, qkv, 1024, 1024, 3072, 0);
  rope_inplace_k<<<2048, 256, 0, stream>>>(qkv);
  transpose_v_k<<<dim3(64, 2, 32), tb32, 0, stream>>>(qkv, vT);
  attn_k<<<dim3(16, 32), 256, 0, stream>>>(qkv, vT, attn_out);
  gemm64_bf16_k<<<dim3(8, 64), 256, 0, stream>>>(attn_out, woT, out, 1024, 3072, 1024);
}